// Round 5
// baseline (106785.938 us; speedup 1.0000x reference)
//
#include <hip/hip_runtime.h>
#include <hip/hip_bf16.h>

#define SEQ   4096
#define HID   512
#define GDIM  2048           // 4*HID
#define NSCAN 64             // scan participants (one XCD: 32 CUs x 2 WGs)
#define GRID_SCAN 512        // oversubscribe so some XCD surely fills 64 WGs
#define SPIN_CAP 65536       // fast-poll bound before sticky agent fallback

// ---------------- workspace layout (bytes) ----------------
// [0, 33554432)        : gx  [SEQ][GDIM] f32  (32 MB)
// [+0,     +8192)      : hp  [2][512] u64  {hi=epoch | lo=h_f32_bits}  (sc0/L2)
// [+8192,  +16384)     : hp2 [2][512] u64  mirror                      (agent/MALL)
// [+16384, +16424)     : election: xcnt[8], winlock, winner
#define GX_BYTES   (33554432L)
#define INIT_WORDS 4106      // (16384 + 40)/4

typedef unsigned uint;
typedef uint  v4u __attribute__((ext_vector_type(4)));
typedef uint  v2u __attribute__((ext_vector_type(2)));
typedef _Float16 half2v __attribute__((ext_vector_type(2)));

static __device__ __forceinline__ half2v pack_f16(float a, float b) {
    return __builtin_bit_cast(half2v, __builtin_amdgcn_cvt_pkrtz(a, b));
}

#if __has_builtin(__builtin_amdgcn_fdot2)
#define FDOT2(a,b,c) __builtin_amdgcn_fdot2((a),(b),(c),false)
#else
static __device__ __forceinline__ float FDOT2(half2v a, half2v b, float c) {
    return c + (float)a.x * (float)b.x + (float)a.y * (float)b.y;
}
#endif

// =========================================================
// Kernel A: gx[t][j] = emb[tok[t]] . W_ih[j] + b_ih[j] + b_hh[j]
// 64x64 tile, BK=32, f32.  Block (0,0) also zeroes hp/hp2/election.
// =========================================================
__global__ __launch_bounds__(256) void gemm_gx(
    const int*   __restrict__ tokens,
    const float* __restrict__ emb,
    const float* __restrict__ W_ih,
    const float* __restrict__ b_ih,
    const float* __restrict__ b_hh,
    float*       __restrict__ gx,
    int*         __restrict__ initzone)
{
    __shared__ float As[64][33];
    __shared__ float Bs[64][33];
    __shared__ int   tok_s[64];

    const int tid = threadIdx.x;
    const int j0  = blockIdx.x * 64;
    const int t0  = blockIdx.y * 64;

    if (blockIdx.x == 0 && blockIdx.y == 0) {
        for (int i = tid; i < INIT_WORDS; i += 256) initzone[i] = 0;
    }
    if (tid < 64) tok_s[tid] = tokens[t0 + tid];
    __syncthreads();

    const int i  = tid >> 2;
    const int ko = (tid & 3) * 8;
    const int ty = tid >> 4;
    const int tx = tid & 15;

    const long arow = (long)tok_s[i] * HID;
    const long brow = (long)(j0 + i) * HID;

    float acc[4][4] = {};

    for (int k0 = 0; k0 < HID; k0 += 32) {
        float4 a0 = *(const float4*)&emb[arow + k0 + ko];
        float4 a1 = *(const float4*)&emb[arow + k0 + ko + 4];
        float4 b0 = *(const float4*)&W_ih[brow + k0 + ko];
        float4 b1 = *(const float4*)&W_ih[brow + k0 + ko + 4];
        As[i][ko+0]=a0.x; As[i][ko+1]=a0.y; As[i][ko+2]=a0.z; As[i][ko+3]=a0.w;
        As[i][ko+4]=a1.x; As[i][ko+5]=a1.y; As[i][ko+6]=a1.z; As[i][ko+7]=a1.w;
        Bs[i][ko+0]=b0.x; Bs[i][ko+1]=b0.y; Bs[i][ko+2]=b0.z; Bs[i][ko+3]=b0.w;
        Bs[i][ko+4]=b1.x; Bs[i][ko+5]=b1.y; Bs[i][ko+6]=b1.z; Bs[i][ko+7]=b1.w;
        __syncthreads();

        #pragma unroll
        for (int kk = 0; kk < 32; ++kk) {
            float av0 = As[ty*4+0][kk], av1 = As[ty*4+1][kk];
            float av2 = As[ty*4+2][kk], av3 = As[ty*4+3][kk];
            float bv0 = Bs[tx*4+0][kk], bv1 = Bs[tx*4+1][kk];
            float bv2 = Bs[tx*4+2][kk], bv3 = Bs[tx*4+3][kk];
            acc[0][0] += av0*bv0; acc[0][1] += av0*bv1; acc[0][2] += av0*bv2; acc[0][3] += av0*bv3;
            acc[1][0] += av1*bv0; acc[1][1] += av1*bv1; acc[1][2] += av1*bv2; acc[1][3] += av1*bv3;
            acc[2][0] += av2*bv0; acc[2][1] += av2*bv1; acc[2][2] += av2*bv2; acc[2][3] += av2*bv3;
            acc[3][0] += av3*bv0; acc[3][1] += av3*bv1; acc[3][2] += av3*bv2; acc[3][3] += av3*bv3;
        }
        __syncthreads();
    }

    #pragma unroll
    for (int m = 0; m < 4; ++m) {
        const long t = t0 + ty*4 + m;
        #pragma unroll
        for (int n = 0; n < 4; ++n) {
            const int j = j0 + tx*4 + n;
            gx[t*GDIM + j] = acc[m][n] + b_ih[j] + b_hh[j];
        }
    }
}

// =========================================================
// Kernel B: persistent LSTM scan, XCD-colocated, L2-scope sync,
// with agent-scope mirror fallback (hang-proof).
// =========================================================
__global__ __launch_bounds__(256, 2) void lstm_scan(
    const float* __restrict__ gx,
    const float* __restrict__ W_hh,
    unsigned long long* hp,    // [2][512] sc0 fast buffer
    unsigned long long* hp2,   // [2][512] agent-scope mirror
    uint*  elect,              // xcnt[8], winlock, winner
    float* out)                // [1024] = h ++ c
{
    __shared__ uint s_part[2];
    __shared__ uint hs16[2][8 * 36];   // f16-packed h, chunk c at 36c

    const int tid = threadIdx.x;

    // ---------------- election (one XCD wins) ----------------
    uint xcd;
    asm volatile("s_getreg_b32 %0, hwreg(HW_REG_XCC_ID)" : "=s"(xcd));
    xcd &= 7u;
    if (tid == 0) {
        uint* xcnt    = elect;
        uint* winlock = elect + 8;
        uint* winner  = elect + 9;
        uint slot = __hip_atomic_fetch_add(&xcnt[xcd], 1u,
                        __ATOMIC_RELAXED, __HIP_MEMORY_SCOPE_AGENT);
        if (slot == NSCAN - 1) {
            if (__hip_atomic_fetch_add(winlock, 1u,
                    __ATOMIC_ACQ_REL, __HIP_MEMORY_SCOPE_AGENT) == 0)
                __hip_atomic_store(winner, xcd + 1u,
                    __ATOMIC_RELEASE, __HIP_MEMORY_SCOPE_AGENT);
        }
        uint wn;
        while ((wn = __hip_atomic_load(winner,
                    __ATOMIC_ACQUIRE, __HIP_MEMORY_SCOPE_AGENT)) == 0)
            __builtin_amdgcn_s_sleep(2);
        s_part[0] = (wn - 1u == xcd && slot < NSCAN) ? 1u : 0u;
        s_part[1] = slot;
    }
    __syncthreads();
    if (!s_part[0]) return;
    const int w = (int)s_part[1];

    // ---------------- lane geometry ----------------
    const int wv = tid >> 6;       // wave id
    const int l  = tid & 63;
    const int r  = l >> 3;         // row 0..7 = gate g*2 + unit uu
    const int c  = l & 7;          // k-chunk 0..7 (64 k each)
    const int g  = r >> 1;
    const int uu = r & 1;
    const int unit  = w * 8 + wv * 2 + uu;
    const int grow  = g * 512 + unit;           // gate row in [0,2048)
    const int selu  = (l >= 32) ? 1 : 0;
    const int punit = w * 8 + wv * 2 + selu;

    // ---------------- W_hh row segment into registers (f16) ----------------
    half2v wreg[32];
    {
        const float* wsrc = W_hh + (long)grow * HID + c * 64;
        #pragma unroll
        for (int j = 0; j < 32; ++j) {
            float2 wp = *(const float2*)&wsrc[2 * j];
            wreg[j] = pack_f16(wp.x, wp.y);
        }
    }

    float cstate = 0.0f;
    float gxcur = (c == 0) ? gx[grow] : 0.0f;

    const int cc  = tid >> 5;
    const int pos = tid & 31;
    bool slow = false;             // sticky fallback flag

    for (int t = 0; t < SEQ; ++t) {
        const int p = t & 1;

        // ---- acquire this thread's 2 pairs ----
        v4u pv;
        bool ok = false;
        if (!slow) {
            const unsigned long long* src = hp + (long)p * HID + 2 * tid;
            for (int spin = 0; spin < SPIN_CAP; ++spin) {
                asm volatile("global_load_dwordx4 %0, %1, off sc0\n\t"
                             "s_waitcnt vmcnt(0)"
                             : "=v"(pv) : "v"(src) : "memory");
                if (pv.y == (uint)t && pv.w == (uint)t) { ok = true; break; }
            }
            if (!ok) slow = true;
        }
        if (slow && !ok) {
            const unsigned long long* s2 = hp2 + (long)p * HID + 2 * tid;
            unsigned long long v0, v1;
            do {
                v0 = __hip_atomic_load(s2, __ATOMIC_RELAXED, __HIP_MEMORY_SCOPE_AGENT);
            } while ((uint)(v0 >> 32) != (uint)t);
            do {
                v1 = __hip_atomic_load(s2 + 1, __ATOMIC_RELAXED, __HIP_MEMORY_SCOPE_AGENT);
            } while ((uint)(v1 >> 32) != (uint)t);
            pv.x = (uint)v0; pv.y = (uint)(v0 >> 32);
            pv.z = (uint)v1; pv.w = (uint)(v1 >> 32);
        }

        // f16-pack and share via LDS
        half2v h2 = pack_f16(__uint_as_float(pv.x), __uint_as_float(pv.z));
        hs16[p][cc * 36 + pos] = *(uint*)&h2;

        // prefetch next step's gx (overlaps with compute)
        float gxn = 0.0f;
        if (c == 0 && t + 1 < SEQ) gxn = gx[(long)(t + 1) * GDIM + grow];

        __syncthreads();

        // ---- load h chunk c (64 f16 = 32 u32) ----
        uint hh[32];
        #pragma unroll
        for (int j = 0; j < 32; j += 4)
            *(v4u*)&hh[j] = *(const v4u*)&hs16[p][c * 36 + j];

        // ---- 64-deep f16 dot for row r, chunk c ----
        float acc = 0.0f;
        #pragma unroll
        for (int j = 0; j < 32; ++j)
            acc = FDOT2(wreg[j], *(half2v*)&hh[j], acc);

        // reduce across the 8 k-chunks (lane bits 0..2)
        acc += __shfl_xor(acc, 1, 64);
        acc += __shfl_xor(acc, 2, 64);
        acc += __shfl_xor(acc, 4, 64);

        const float accg = acc + gxcur;   // valid on c==0 lanes
        gxcur = gxn;

        // gather this half-wave's unit gates from the c==0 lanes
        const float gi = __shfl(accg, 8 * (0 + selu), 64);
        const float gf = __shfl(accg, 8 * (2 + selu), 64);
        const float gc = __shfl(accg, 8 * (4 + selu), 64);
        const float go = __shfl(accg, 8 * (6 + selu), 64);

        const float ig = 1.0f / (1.0f + __expf(-gi));
        const float fg = 1.0f / (1.0f + __expf(-gf));
        const float gg = 2.0f / (1.0f + __expf(-2.0f * gc)) - 1.0f;
        const float og = 1.0f / (1.0f + __expf(-go));
        cstate = fg * cstate + ig * gg;
        const float tc = 2.0f / (1.0f + __expf(-2.0f * cstate)) - 1.0f;
        const float hnew = og * tc;

        // ---- dual publish (lanes 0 and 32 of each wave) ----
        if ((l & 31) == 0) {
            const long off = (long)((t + 1) & 1) * HID + punit;
            v2u pub;
            pub.x = __float_as_uint(hnew);
            pub.y = (uint)(t + 1);
            asm volatile("global_store_dwordx2 %0, %1, off sc0"
                         :: "v"(hp + off), "v"(pub) : "memory");
            const unsigned long long mv =
                ((unsigned long long)(uint)(t + 1) << 32) | __float_as_uint(hnew);
            __hip_atomic_store(hp2 + off, mv,
                               __ATOMIC_RELAXED, __HIP_MEMORY_SCOPE_AGENT);
            if (t == SEQ - 1) {
                out[punit]       = hnew;
                out[HID + punit] = cstate;
            }
        }
        // no trailing barrier: next iteration uses the other hs16 parity
    }
}

// =========================================================
extern "C" void kernel_launch(void* const* d_in, const int* in_sizes, int n_in,
                              void* d_out, int out_size, void* d_ws, size_t ws_size,
                              hipStream_t stream)
{
    const int*   tokens = (const int*)  d_in[0];
    const float* emb    = (const float*)d_in[1];
    const float* W_ih   = (const float*)d_in[2];
    const float* W_hh   = (const float*)d_in[3];
    const float* b_ih   = (const float*)d_in[4];
    const float* b_hh   = (const float*)d_in[5];
    float* out = (float*)d_out;

    char* ws = (char*)d_ws;
    float*              gx    = (float*)ws;
    unsigned long long* hp    = (unsigned long long*)(ws + GX_BYTES);
    unsigned long long* hp2   = (unsigned long long*)(ws + GX_BYTES + 8192);
    uint*               elect = (uint*)(ws + GX_BYTES + 16384);
    int*                initz = (int*)(ws + GX_BYTES);

    gemm_gx<<<dim3(GDIM / 64, SEQ / 64), 256, 0, stream>>>(
        tokens, emb, W_ih, b_ih, b_hh, gx, initz);

    lstm_scan<<<dim3(GRID_SCAN), 256, 0, stream>>>(gx, W_hh, hp, hp2, elect, out);
}

// Round 8
// 8081.326 us; speedup vs baseline: 13.2139x; 13.2139x over previous
//
#include <hip/hip_runtime.h>
#include <hip/hip_bf16.h>

#define SEQ   4096
#define HID   512
#define GDIM  2048           // 4*HID
#define NSCAN 64             // scan participants (one XCD: 32 CUs x 2 WGs)
#define GRID_SCAN 512        // oversubscribe so some XCD surely fills 64 WGs
#define SPIN_CAP 65536       // (dead when slow starts true; kept for structure)

// ---------------- workspace layout (bytes) ----------------
// [0, 33554432)        : gx  [SEQ][GDIM] f32  (32 MB)
// [+0,     +8192)      : hp  [2][512] u64  {hi=epoch | lo=h_f32_bits}  (sc0/L2)
// [+8192,  +16384)     : hp2 [2][512] u64  mirror                      (agent/MALL)
// [+16384, +16424)     : election: xcnt[8], winlock, winner
#define GX_BYTES   (33554432L)
#define INIT_WORDS 4106      // (16384 + 40)/4

typedef unsigned uint;
typedef uint  v4u __attribute__((ext_vector_type(4)));
typedef uint  v2u __attribute__((ext_vector_type(2)));
typedef _Float16 half2v __attribute__((ext_vector_type(2)));

static __device__ __forceinline__ half2v pack_f16(float a, float b) {
    return __builtin_bit_cast(half2v, __builtin_amdgcn_cvt_pkrtz(a, b));
}

#if __has_builtin(__builtin_amdgcn_fdot2)
#define FDOT2(a,b,c) __builtin_amdgcn_fdot2((a),(b),(c),false)
#else
static __device__ __forceinline__ float FDOT2(half2v a, half2v b, float c) {
    return c + (float)a.x * (float)b.x + (float)a.y * (float)b.y;
}
#endif

// =========================================================
// Kernel A: gx[t][j] = emb[tok[t]] . W_ih[j] + b_ih[j] + b_hh[j]
// 64x64 tile, BK=32, f32.  Block (0,0) also zeroes hp/hp2/election.
// =========================================================
__global__ __launch_bounds__(256) void gemm_gx(
    const int*   __restrict__ tokens,
    const float* __restrict__ emb,
    const float* __restrict__ W_ih,
    const float* __restrict__ b_ih,
    const float* __restrict__ b_hh,
    float*       __restrict__ gx,
    int*         __restrict__ initzone)
{
    __shared__ float As[64][33];
    __shared__ float Bs[64][33];
    __shared__ int   tok_s[64];

    const int tid = threadIdx.x;
    const int j0  = blockIdx.x * 64;
    const int t0  = blockIdx.y * 64;

    if (blockIdx.x == 0 && blockIdx.y == 0) {
        for (int i = tid; i < INIT_WORDS; i += 256) initzone[i] = 0;
    }
    if (tid < 64) tok_s[tid] = tokens[t0 + tid];
    __syncthreads();

    const int i  = tid >> 2;
    const int ko = (tid & 3) * 8;
    const int ty = tid >> 4;
    const int tx = tid & 15;

    const long arow = (long)tok_s[i] * HID;
    const long brow = (long)(j0 + i) * HID;

    float acc[4][4] = {};

    for (int k0 = 0; k0 < HID; k0 += 32) {
        float4 a0 = *(const float4*)&emb[arow + k0 + ko];
        float4 a1 = *(const float4*)&emb[arow + k0 + ko + 4];
        float4 b0 = *(const float4*)&W_ih[brow + k0 + ko];
        float4 b1 = *(const float4*)&W_ih[brow + k0 + ko + 4];
        As[i][ko+0]=a0.x; As[i][ko+1]=a0.y; As[i][ko+2]=a0.z; As[i][ko+3]=a0.w;
        As[i][ko+4]=a1.x; As[i][ko+5]=a1.y; As[i][ko+6]=a1.z; As[i][ko+7]=a1.w;
        Bs[i][ko+0]=b0.x; Bs[i][ko+1]=b0.y; Bs[i][ko+2]=b0.z; Bs[i][ko+3]=b0.w;
        Bs[i][ko+4]=b1.x; Bs[i][ko+5]=b1.y; Bs[i][ko+6]=b1.z; Bs[i][ko+7]=b1.w;
        __syncthreads();

        #pragma unroll
        for (int kk = 0; kk < 32; ++kk) {
            float av0 = As[ty*4+0][kk], av1 = As[ty*4+1][kk];
            float av2 = As[ty*4+2][kk], av3 = As[ty*4+3][kk];
            float bv0 = Bs[tx*4+0][kk], bv1 = Bs[tx*4+1][kk];
            float bv2 = Bs[tx*4+2][kk], bv3 = Bs[tx*4+3][kk];
            acc[0][0] += av0*bv0; acc[0][1] += av0*bv1; acc[0][2] += av0*bv2; acc[0][3] += av0*bv3;
            acc[1][0] += av1*bv0; acc[1][1] += av1*bv1; acc[1][2] += av1*bv2; acc[1][3] += av1*bv3;
            acc[2][0] += av2*bv0; acc[2][1] += av2*bv1; acc[2][2] += av2*bv2; acc[2][3] += av2*bv3;
            acc[3][0] += av3*bv0; acc[3][1] += av3*bv1; acc[3][2] += av3*bv2; acc[3][3] += av3*bv3;
        }
        __syncthreads();
    }

    #pragma unroll
    for (int m = 0; m < 4; ++m) {
        const long t = t0 + ty*4 + m;
        #pragma unroll
        for (int n = 0; n < 4; ++n) {
            const int j = j0 + tx*4 + n;
            gx[t*GDIM + j] = acc[m][n] + b_ih[j] + b_hh[j];
        }
    }
}

// =========================================================
// Kernel B: EXACT R4 structure (the kernel that PASSED), with the
// sc0 fast path disabled (slow = true from step 0). Election, dual
// publish, hp/hp2 split, grid 512 all preserved bit-identically.
// =========================================================
__global__ __launch_bounds__(256, 2) void lstm_scan(
    const float* __restrict__ gx,
    const float* __restrict__ W_hh,
    unsigned long long* hp,    // [2][512] sc0 fast buffer (published, unused for poll)
    unsigned long long* hp2,   // [2][512] agent-scope mirror (the poll source)
    uint*  elect,              // xcnt[8], winlock, winner
    float* out)                // [1024] = h ++ c
{
    __shared__ uint s_part[2];
    __shared__ uint hs16[2][8 * 36];   // f16-packed h, chunk c at 36c

    const int tid = threadIdx.x;

    // ---------------- election (one XCD wins) ----------------
    uint xcd;
    asm volatile("s_getreg_b32 %0, hwreg(HW_REG_XCC_ID)" : "=s"(xcd));
    xcd &= 7u;
    if (tid == 0) {
        uint* xcnt    = elect;
        uint* winlock = elect + 8;
        uint* winner  = elect + 9;
        uint slot = __hip_atomic_fetch_add(&xcnt[xcd], 1u,
                        __ATOMIC_RELAXED, __HIP_MEMORY_SCOPE_AGENT);
        if (slot == NSCAN - 1) {
            if (__hip_atomic_fetch_add(winlock, 1u,
                    __ATOMIC_ACQ_REL, __HIP_MEMORY_SCOPE_AGENT) == 0)
                __hip_atomic_store(winner, xcd + 1u,
                    __ATOMIC_RELEASE, __HIP_MEMORY_SCOPE_AGENT);
        }
        uint wn;
        while ((wn = __hip_atomic_load(winner,
                    __ATOMIC_ACQUIRE, __HIP_MEMORY_SCOPE_AGENT)) == 0)
            __builtin_amdgcn_s_sleep(2);
        s_part[0] = (wn - 1u == xcd && slot < NSCAN) ? 1u : 0u;
        s_part[1] = slot;
    }
    __syncthreads();
    if (!s_part[0]) return;
    const int w = (int)s_part[1];

    // ---------------- lane geometry ----------------
    const int wv = tid >> 6;       // wave id
    const int l  = tid & 63;
    const int r  = l >> 3;         // row 0..7 = gate g*2 + unit uu
    const int c  = l & 7;          // k-chunk 0..7 (64 k each)
    const int g  = r >> 1;
    const int uu = r & 1;
    const int unit  = w * 8 + wv * 2 + uu;
    const int grow  = g * 512 + unit;           // gate row in [0,2048)
    const int selu  = (l >= 32) ? 1 : 0;
    const int punit = w * 8 + wv * 2 + selu;

    // ---------------- W_hh row segment into registers (f16) ----------------
    half2v wreg[32];
    {
        const float* wsrc = W_hh + (long)grow * HID + c * 64;
        #pragma unroll
        for (int j = 0; j < 32; ++j) {
            float2 wp = *(const float2*)&wsrc[2 * j];
            wreg[j] = pack_f16(wp.x, wp.y);
        }
    }

    float cstate = 0.0f;
    float gxcur = (c == 0) ? gx[grow] : 0.0f;

    const int cc  = tid >> 5;
    const int pos = tid & 31;
    bool slow = true;              // CHANGED (was false): skip sc0 purgatory

    for (int t = 0; t < SEQ; ++t) {
        const int p = t & 1;

        // ---- acquire this thread's 2 pairs ----
        v4u pv;
        bool ok = false;
        if (!slow) {
            const unsigned long long* src = hp + (long)p * HID + 2 * tid;
            for (int spin = 0; spin < SPIN_CAP; ++spin) {
                asm volatile("global_load_dwordx4 %0, %1, off sc0\n\t"
                             "s_waitcnt vmcnt(0)"
                             : "=v"(pv) : "v"(src) : "memory");
                if (pv.y == (uint)t && pv.w == (uint)t) { ok = true; break; }
            }
            if (!ok) slow = true;
        }
        if (slow && !ok) {
            const unsigned long long* s2 = hp2 + (long)p * HID + 2 * tid;
            unsigned long long v0, v1;
            do {
                v0 = __hip_atomic_load(s2, __ATOMIC_RELAXED, __HIP_MEMORY_SCOPE_AGENT);
            } while ((uint)(v0 >> 32) != (uint)t);
            do {
                v1 = __hip_atomic_load(s2 + 1, __ATOMIC_RELAXED, __HIP_MEMORY_SCOPE_AGENT);
            } while ((uint)(v1 >> 32) != (uint)t);
            pv.x = (uint)v0; pv.y = (uint)(v0 >> 32);
            pv.z = (uint)v1; pv.w = (uint)(v1 >> 32);
        }

        // f16-pack and share via LDS
        half2v h2 = pack_f16(__uint_as_float(pv.x), __uint_as_float(pv.z));
        hs16[p][cc * 36 + pos] = *(uint*)&h2;

        // prefetch next step's gx (overlaps with compute)
        float gxn = 0.0f;
        if (c == 0 && t + 1 < SEQ) gxn = gx[(long)(t + 1) * GDIM + grow];

        __syncthreads();

        // ---- load h chunk c (64 f16 = 32 u32) ----
        uint hh[32];
        #pragma unroll
        for (int j = 0; j < 32; j += 4)
            *(v4u*)&hh[j] = *(const v4u*)&hs16[p][c * 36 + j];

        // ---- 64-deep f16 dot for row r, chunk c ----
        float acc = 0.0f;
        #pragma unroll
        for (int j = 0; j < 32; ++j)
            acc = FDOT2(wreg[j], *(half2v*)&hh[j], acc);

        // reduce across the 8 k-chunks (lane bits 0..2)
        acc += __shfl_xor(acc, 1, 64);
        acc += __shfl_xor(acc, 2, 64);
        acc += __shfl_xor(acc, 4, 64);

        const float accg = acc + gxcur;   // valid on c==0 lanes
        gxcur = gxn;

        // gather this half-wave's unit gates from the c==0 lanes
        const float gi = __shfl(accg, 8 * (0 + selu), 64);
        const float gf = __shfl(accg, 8 * (2 + selu), 64);
        const float gc = __shfl(accg, 8 * (4 + selu), 64);
        const float go = __shfl(accg, 8 * (6 + selu), 64);

        const float ig = 1.0f / (1.0f + __expf(-gi));
        const float fg = 1.0f / (1.0f + __expf(-gf));
        const float gg = 2.0f / (1.0f + __expf(-2.0f * gc)) - 1.0f;
        const float og = 1.0f / (1.0f + __expf(-go));
        cstate = fg * cstate + ig * gg;
        const float tc = 2.0f / (1.0f + __expf(-2.0f * cstate)) - 1.0f;
        const float hnew = og * tc;

        // ---- dual publish (lanes 0 and 32 of each wave) ----
        if ((l & 31) == 0) {
            const long off = (long)((t + 1) & 1) * HID + punit;
            v2u pub;
            pub.x = __float_as_uint(hnew);
            pub.y = (uint)(t + 1);
            asm volatile("global_store_dwordx2 %0, %1, off sc0"
                         :: "v"(hp + off), "v"(pub) : "memory");
            const unsigned long long mv =
                ((unsigned long long)(uint)(t + 1) << 32) | __float_as_uint(hnew);
            __hip_atomic_store(hp2 + off, mv,
                               __ATOMIC_RELAXED, __HIP_MEMORY_SCOPE_AGENT);
            if (t == SEQ - 1) {
                out[punit]       = hnew;
                out[HID + punit] = cstate;
            }
        }
        // no trailing barrier: next iteration uses the other hs16 parity
    }
}

// =========================================================
extern "C" void kernel_launch(void* const* d_in, const int* in_sizes, int n_in,
                              void* d_out, int out_size, void* d_ws, size_t ws_size,
                              hipStream_t stream)
{
    const int*   tokens = (const int*)  d_in[0];
    const float* emb    = (const float*)d_in[1];
    const float* W_ih   = (const float*)d_in[2];
    const float* W_hh   = (const float*)d_in[3];
    const float* b_ih   = (const float*)d_in[4];
    const float* b_hh   = (const float*)d_in[5];
    float* out = (float*)d_out;

    char* ws = (char*)d_ws;
    float*              gx    = (float*)ws;
    unsigned long long* hp    = (unsigned long long*)(ws + GX_BYTES);
    unsigned long long* hp2   = (unsigned long long*)(ws + GX_BYTES + 8192);
    uint*               elect = (uint*)(ws + GX_BYTES + 16384);
    int*                initz = (int*)(ws + GX_BYTES);

    gemm_gx<<<dim3(GDIM / 64, SEQ / 64), 256, 0, stream>>>(
        tokens, emb, W_ih, b_ih, b_hh, gx, initz);

    lstm_scan<<<dim3(GRID_SCAN), 256, 0, stream>>>(gx, W_hh, hp, hp2, elect, out);
}